// Round 1
// baseline (541.704 us; speedup 1.0000x reference)
//
#include <hip/hip_runtime.h>
#include <hip/hip_bf16.h>

#define NN 100000
#define EE 1600000
#define INC 256
#define OUTC 128

typedef short bf16x8 __attribute__((ext_vector_type(8)));
typedef float f32x4 __attribute__((ext_vector_type(4)));

static __device__ __forceinline__ unsigned short f2bf(float f){
    unsigned u = __builtin_bit_cast(unsigned, f);
    u += 0x7fffu + ((u >> 16) & 1u);
    return (unsigned short)(u >> 16);
}
static __device__ __forceinline__ float bf2f(unsigned short h){
    unsigned u = ((unsigned)h) << 16;
    return __builtin_bit_cast(float, u);
}

// ---------- degree count ----------
__global__ void deg_kernel(const int* __restrict__ col, unsigned* __restrict__ deg, int E){
    for (int i = blockIdx.x*blockDim.x + threadIdx.x; i < E; i += gridDim.x*blockDim.x)
        atomicAdd(&deg[col[i]], 1u);
}

// ---------- exclusive scan over deg -> offs (single block, N=100K) ----------
__global__ void scan_kernel(const unsigned* __restrict__ deg, unsigned* __restrict__ offs, int Nn){
    __shared__ unsigned part[1024];
    int t = threadIdx.x;
    int chunk = (Nn + 1023) >> 10;
    int lo = min(t*chunk, Nn), hi = min(lo + chunk, Nn);
    unsigned s = 0;
    for (int i = lo; i < hi; ++i) s += deg[i];
    part[t] = s;
    __syncthreads();
    for (int off = 1; off < 1024; off <<= 1){
        unsigned v = (t >= off) ? part[t - off] : 0u;
        __syncthreads();
        part[t] += v;
        __syncthreads();
    }
    unsigned run = part[t] - s;            // exclusive prefix of this chunk
    for (int i = lo; i < hi; ++i){ offs[i] = run; run += deg[i]; }
    if (t == 1023) offs[Nn] = run;
}

// ---------- dinv + cursor init ----------
__global__ void dinv_cursor_kernel(const unsigned* __restrict__ deg, const unsigned* __restrict__ offs,
                                   float* __restrict__ dinv, unsigned* __restrict__ cursor, int Nn){
    int i = blockIdx.x*blockDim.x + threadIdx.x;
    if (i < Nn){
        unsigned d = deg[i];
        dinv[i] = d ? rsqrtf((float)d) : 0.f;
        cursor[i] = offs[i];
    }
}

// ---------- counting-sort fill: edges grouped by target ----------
__global__ void fill_kernel(const int* __restrict__ ei, unsigned* __restrict__ cursor,
                            unsigned* __restrict__ erow, int E){
    for (int e = blockIdx.x*blockDim.x + threadIdx.x; e < E; e += gridDim.x*blockDim.x){
        int r = ei[e];
        int c = ei[E + e];
        unsigned pos = atomicAdd(&cursor[c], 1u);
        erow[pos] = (unsigned)r;
    }
}

// ---------- GEMM: h2 = perm/sign( x @ W^T ) in bf16 ----------
// block = 256 threads (4 waves), 64 rows/block, full 128 cols, K=256
// W staged in LDS pre-arranged in exact B-fragment order: [s][t][lane][r]
__launch_bounds__(256, 2)
__global__ void gemm_kernel(const float* __restrict__ x, const float* __restrict__ w,
                            unsigned short* __restrict__ h2, int Nn){
    __shared__ unsigned short bfrag[8*8*64*8];   // 64 KB
    int tid = threadIdx.x;
    for (int idx = tid; idx < 8*8*64*8; idx += 256){
        int r = idx & 7, l = (idx >> 3) & 63, t = (idx >> 9) & 7, s = idx >> 12;
        int n = t*16 + (l & 15);
        int k = s*32 + ((l >> 4) << 3) + r;
        bfrag[idx] = f2bf(w[n*INC + k]);
    }
    __syncthreads();

    int wave = tid >> 6, lane = tid & 63;
    int mrow = blockIdx.x*64 + wave*16 + (lane & 15);
    const float* xr = x + (size_t)min(mrow, Nn-1) * INC;
    int kg = (lane >> 4) << 3;   // 0,8,16,24

    f32x4 acc[8];
    #pragma unroll
    for (int t = 0; t < 8; ++t) acc[t] = (f32x4){0.f,0.f,0.f,0.f};

    #pragma unroll
    for (int s = 0; s < 8; ++s){
        const float4* p = (const float4*)(xr + s*32 + kg);
        float4 a0 = p[0], a1 = p[1];
        bf16x8 af;
        af[0]=f2bf(a0.x); af[1]=f2bf(a0.y); af[2]=f2bf(a0.z); af[3]=f2bf(a0.w);
        af[4]=f2bf(a1.x); af[5]=f2bf(a1.y); af[6]=f2bf(a1.z); af[7]=f2bf(a1.w);
        #pragma unroll
        for (int t = 0; t < 8; ++t){
            const bf16x8 bf = *(const bf16x8*)&bfrag[((s*8 + t)*64 + lane)*8];
            acc[t] = __builtin_amdgcn_mfma_f32_16x16x32_bf16(af, bf, acc[t], 0, 0, 0);
        }
    }

    int rbase = blockIdx.x*64 + wave*16 + ((lane >> 4) << 2);
    #pragma unroll
    for (int t = 0; t < 8; ++t){
        int o  = t*16 + (lane & 15);          // original output channel
        int dc = (o + 64) & 127;              // rolled destination column
        float sgn = (o < 64) ? 1.f : -1.f;    // negate-second-half folded through roll
        #pragma unroll
        for (int r = 0; r < 4; ++r){
            int row = rbase + r;
            if (row < Nn) h2[(size_t)row*OUTC + dc] = f2bf(sgn * acc[t][r]);
        }
    }
}

// ---------- gather-aggregate: one wave per node, 2 edges/iter ----------
__launch_bounds__(256)
__global__ void gather_kernel(const unsigned short* __restrict__ h2,
                              const unsigned* __restrict__ offs,
                              const unsigned* __restrict__ erow,
                              const float* __restrict__ dinv,
                              float* __restrict__ out, int Nn){
    int node = blockIdx.x*4 + (threadIdx.x >> 6);
    if (node >= Nn) return;
    int lane = threadIdx.x & 63;
    unsigned s = offs[node], e = offs[node+1];
    int half = lane >> 5;          // which edge of the pair
    int cb = (lane & 31) << 2;     // 4 columns per lane

    float a0=0.f, a1=0.f, a2=0.f, a3=0.f;
    for (unsigned p = s; p < e; p += 2){
        unsigned idx = p + half;
        float wgt = 0.f; unsigned row = 0;
        if (idx < e){ row = erow[idx]; wgt = dinv[row]; }
        ushort4 v = *(const ushort4*)(h2 + (size_t)row*OUTC + cb);
        a0 += wgt * bf2f(v.x);
        a1 += wgt * bf2f(v.y);
        a2 += wgt * bf2f(v.z);
        a3 += wgt * bf2f(v.w);
    }
    a0 += __shfl_down(a0, 32);
    a1 += __shfl_down(a1, 32);
    a2 += __shfl_down(a2, 32);
    a3 += __shfl_down(a3, 32);
    if (half == 0){
        float wc = dinv[node];
        float4 o = {a0*wc, a1*wc, a2*wc, a3*wc};
        *(float4*)(out + (size_t)node*OUTC + cb) = o;
    }
}

extern "C" void kernel_launch(void* const* d_in, const int* in_sizes, int n_in,
                              void* d_out, int out_size, void* d_ws, size_t ws_size,
                              hipStream_t stream){
    const float* x  = (const float*)d_in[0];
    const int*   ei = (const int*)d_in[1];      // [2][E]: row then col
    const float* w  = (const float*)d_in[2];    // [128][256]
    float* out = (float*)d_out;

    char* ws = (char*)d_ws;
    size_t off = 0;
    auto alloc = [&](size_t b) -> char* {
        char* p = ws + off;
        off += (b + 255) & ~(size_t)255;
        return p;
    };
    unsigned* deg    = (unsigned*)alloc((size_t)NN*4);
    unsigned* offs   = (unsigned*)alloc((size_t)(NN+1)*4);
    unsigned* cursor = (unsigned*)alloc((size_t)NN*4);
    float*    dinv   = (float*)  alloc((size_t)NN*4);
    unsigned* erow   = (unsigned*)alloc((size_t)EE*4);
    unsigned short* h2 = (unsigned short*)alloc((size_t)NN*OUTC*2);

    hipMemsetAsync(deg, 0, (size_t)NN*4, stream);
    deg_kernel<<<2048, 256, 0, stream>>>(ei + EE, deg, EE);
    scan_kernel<<<1, 1024, 0, stream>>>(deg, offs, NN);
    dinv_cursor_kernel<<<(NN+255)/256, 256, 0, stream>>>(deg, offs, dinv, cursor, NN);
    fill_kernel<<<2048, 256, 0, stream>>>(ei, cursor, erow, EE);
    gemm_kernel<<<(NN+63)/64, 256, 0, stream>>>(x, w, h2, NN);
    gather_kernel<<<(NN+3)/4, 256, 0, stream>>>(h2, offs, erow, dinv, out, NN);
}

// Round 2
// 413.618 us; speedup vs baseline: 1.3097x; 1.3097x over previous
//
#include <hip/hip_runtime.h>
#include <hip/hip_bf16.h>

#define NN 100000
#define EE 1600000
#define INC 256
#define OUTC 128
#define SCAN_BLK 1024   // elements per scan1 block
#define NB1 ((NN + SCAN_BLK - 1) / SCAN_BLK)   // 98

typedef short bf16x8 __attribute__((ext_vector_type(8)));
typedef float f32x4 __attribute__((ext_vector_type(4)));

static __device__ __forceinline__ unsigned short f2bf(float f){
    unsigned u = __builtin_bit_cast(unsigned, f);
    u += 0x7fffu + ((u >> 16) & 1u);
    return (unsigned short)(u >> 16);
}
static __device__ __forceinline__ float bf2f(unsigned short h){
    unsigned u = ((unsigned)h) << 16;
    return __builtin_bit_cast(float, u);
}

// ---------- degree count ----------
__global__ void deg_kernel(const int* __restrict__ col, unsigned* __restrict__ deg, int E){
    for (int i = blockIdx.x*blockDim.x + threadIdx.x; i < E; i += gridDim.x*blockDim.x)
        atomicAdd(&deg[col[i]], 1u);
}

// ---------- scan level 1: per-block exclusive scan (1024 elems / 256 thr) ----------
__global__ void scan1_kernel(const unsigned* __restrict__ deg, unsigned* __restrict__ offs,
                             unsigned* __restrict__ bsum, int Nn){
    __shared__ unsigned tmp[256];
    int t = threadIdx.x;
    int base = blockIdx.x*SCAN_BLK + t*4;
    unsigned v0=0, v1=0, v2=0, v3=0;
    if (base + 3 < Nn){
        uint4 u = *(const uint4*)(deg + base);
        v0=u.x; v1=u.y; v2=u.z; v3=u.w;
    } else {
        if (base   < Nn) v0 = deg[base];
        if (base+1 < Nn) v1 = deg[base+1];
        if (base+2 < Nn) v2 = deg[base+2];
        if (base+3 < Nn) v3 = deg[base+3];
    }
    unsigned s = v0+v1+v2+v3;
    tmp[t] = s;
    __syncthreads();
    for (int off = 1; off < 256; off <<= 1){
        unsigned x = (t >= off) ? tmp[t-off] : 0u;
        __syncthreads();
        tmp[t] += x;
        __syncthreads();
    }
    unsigned run = tmp[t] - s;   // exclusive prefix within block
    if (base   < Nn) offs[base]   = run; run += v0;
    if (base+1 < Nn) offs[base+1] = run; run += v1;
    if (base+2 < Nn) offs[base+2] = run; run += v2;
    if (base+3 < Nn) offs[base+3] = run;
    if (t == 255) bsum[blockIdx.x] = tmp[255];
}

// ---------- scan level 2: exclusive scan of the 98 block sums ----------
__global__ void scan2_kernel(unsigned* __restrict__ bsum, int nb){
    __shared__ unsigned tmp[128];
    int t = threadIdx.x;
    unsigned v = (t < nb) ? bsum[t] : 0u;
    tmp[t] = v;
    __syncthreads();
    for (int off = 1; off < 128; off <<= 1){
        unsigned x = (t >= off) ? tmp[t-off] : 0u;
        __syncthreads();
        tmp[t] += x;
        __syncthreads();
    }
    if (t < nb) bsum[t] = tmp[t] - v;   // exclusive, in-place
}

// ---------- scan level 3 + dinv + cursor init (fused) ----------
__global__ void finalize_kernel(const unsigned* __restrict__ deg, unsigned* __restrict__ offs,
                                const unsigned* __restrict__ bsum,
                                float* __restrict__ dinv, unsigned* __restrict__ cursor, int Nn){
    int i = blockIdx.x*blockDim.x + threadIdx.x;
    if (i < Nn){
        unsigned o = offs[i] + bsum[i / SCAN_BLK];
        offs[i] = o;
        cursor[i] = o;
        unsigned d = deg[i];
        dinv[i] = d ? rsqrtf((float)d) : 0.f;
    }
    if (i == 0) offs[Nn] = EE;   // total edge count is exact
}

// ---------- counting-sort fill: edges grouped by target ----------
__global__ void fill_kernel(const int* __restrict__ ei, unsigned* __restrict__ cursor,
                            unsigned* __restrict__ erow, int E){
    for (int e = blockIdx.x*blockDim.x + threadIdx.x; e < E; e += gridDim.x*blockDim.x){
        int r = ei[e];
        int c = ei[E + e];
        unsigned pos = atomicAdd(&cursor[c], 1u);
        erow[pos] = (unsigned)r;
    }
}

// ---------- GEMM: h2 = dinv[row] * perm/sign( x @ W^T ) in bf16 ----------
__launch_bounds__(256, 2)
__global__ void gemm_kernel(const float* __restrict__ x, const float* __restrict__ w,
                            const float* __restrict__ dinv,
                            unsigned short* __restrict__ h2, int Nn){
    __shared__ unsigned short bfrag[8*8*64*8];   // 64 KB
    int tid = threadIdx.x;
    for (int idx = tid; idx < 8*8*64*8; idx += 256){
        int r = idx & 7, l = (idx >> 3) & 63, t = (idx >> 9) & 7, s = idx >> 12;
        int n = t*16 + (l & 15);
        int k = s*32 + ((l >> 4) << 3) + r;
        bfrag[idx] = f2bf(w[n*INC + k]);
    }
    __syncthreads();

    int wave = tid >> 6, lane = tid & 63;
    int mrow = blockIdx.x*64 + wave*16 + (lane & 15);
    const float* xr = x + (size_t)min(mrow, Nn-1) * INC;
    int kg = (lane >> 4) << 3;   // 0,8,16,24

    f32x4 acc[8];
    #pragma unroll
    for (int t = 0; t < 8; ++t) acc[t] = (f32x4){0.f,0.f,0.f,0.f};

    #pragma unroll
    for (int s = 0; s < 8; ++s){
        const float4* p = (const float4*)(xr + s*32 + kg);
        float4 a0 = p[0], a1 = p[1];
        bf16x8 af;
        af[0]=f2bf(a0.x); af[1]=f2bf(a0.y); af[2]=f2bf(a0.z); af[3]=f2bf(a0.w);
        af[4]=f2bf(a1.x); af[5]=f2bf(a1.y); af[6]=f2bf(a1.z); af[7]=f2bf(a1.w);
        #pragma unroll
        for (int t = 0; t < 8; ++t){
            const bf16x8 bf = *(const bf16x8*)&bfrag[((s*8 + t)*64 + lane)*8];
            acc[t] = __builtin_amdgcn_mfma_f32_16x16x32_bf16(af, bf, acc[t], 0, 0, 0);
        }
    }

    int rbase = blockIdx.x*64 + wave*16 + ((lane >> 4) << 2);
    float sc[4];
    #pragma unroll
    for (int r = 0; r < 4; ++r){
        int row = rbase + r;
        sc[r] = (row < Nn) ? dinv[row] : 0.f;
    }
    #pragma unroll
    for (int t = 0; t < 8; ++t){
        int o  = t*16 + (lane & 15);          // original output channel
        int dc = (o + 64) & 127;              // rolled destination column
        float sgn = (o < 64) ? 1.f : -1.f;    // negate-second-half folded through roll
        #pragma unroll
        for (int r = 0; r < 4; ++r){
            int row = rbase + r;
            if (row < Nn) h2[(size_t)row*OUTC + dc] = f2bf(sgn * sc[r] * acc[t][r]);
        }
    }
}

// ---------- gather-aggregate: one wave per node, 2 edges/iter ----------
__launch_bounds__(256)
__global__ void gather_kernel(const unsigned short* __restrict__ h2,
                              const unsigned* __restrict__ offs,
                              const unsigned* __restrict__ erow,
                              const float* __restrict__ dinv,
                              float* __restrict__ out, int Nn){
    int node = blockIdx.x*4 + (threadIdx.x >> 6);
    if (node >= Nn) return;
    int lane = threadIdx.x & 63;
    unsigned s = offs[node], e = offs[node+1];
    int half = lane >> 5;          // which edge of the pair
    int cb = (lane & 31) << 2;     // 4 columns per lane

    float a0=0.f, a1=0.f, a2=0.f, a3=0.f;
    for (unsigned p = s; p < e; p += 2){
        unsigned idx = p + half;
        if (idx < e){
            unsigned row = erow[idx];
            ushort4 v = *(const ushort4*)(h2 + (size_t)row*OUTC + cb);
            a0 += bf2f(v.x);
            a1 += bf2f(v.y);
            a2 += bf2f(v.z);
            a3 += bf2f(v.w);
        }
    }
    a0 += __shfl_down(a0, 32);
    a1 += __shfl_down(a1, 32);
    a2 += __shfl_down(a2, 32);
    a3 += __shfl_down(a3, 32);
    if (half == 0){
        float wc = dinv[node];
        float4 o = {a0*wc, a1*wc, a2*wc, a3*wc};
        *(float4*)(out + (size_t)node*OUTC + cb) = o;
    }
}

extern "C" void kernel_launch(void* const* d_in, const int* in_sizes, int n_in,
                              void* d_out, int out_size, void* d_ws, size_t ws_size,
                              hipStream_t stream){
    const float* x  = (const float*)d_in[0];
    const int*   ei = (const int*)d_in[1];      // [2][E]: row then col
    const float* w  = (const float*)d_in[2];    // [128][256]
    float* out = (float*)d_out;

    char* ws = (char*)d_ws;
    size_t off = 0;
    auto alloc = [&](size_t b) -> char* {
        char* p = ws + off;
        off += (b + 255) & ~(size_t)255;
        return p;
    };
    unsigned* deg    = (unsigned*)alloc((size_t)NN*4);
    unsigned* offs   = (unsigned*)alloc((size_t)(NN+1)*4);
    unsigned* cursor = (unsigned*)alloc((size_t)NN*4);
    float*    dinv   = (float*)  alloc((size_t)NN*4);
    unsigned* bsum   = (unsigned*)alloc((size_t)NB1*4);
    unsigned* erow   = (unsigned*)alloc((size_t)EE*4);
    unsigned short* h2 = (unsigned short*)alloc((size_t)NN*OUTC*2);

    hipMemsetAsync(deg, 0, (size_t)NN*4, stream);
    deg_kernel<<<2048, 256, 0, stream>>>(ei + EE, deg, EE);
    scan1_kernel<<<NB1, 256, 0, stream>>>(deg, offs, bsum, NN);
    scan2_kernel<<<1, 128, 0, stream>>>(bsum, NB1);
    finalize_kernel<<<(NN+255)/256, 256, 0, stream>>>(deg, offs, bsum, dinv, cursor, NN);
    fill_kernel<<<2048, 256, 0, stream>>>(ei, cursor, erow, EE);
    gemm_kernel<<<(NN+63)/64, 256, 0, stream>>>(x, w, dinv, h2, NN);
    gather_kernel<<<(NN+3)/4, 256, 0, stream>>>(h2, offs, erow, dinv, out, NN);
}